// Round 18
// baseline (46.816 us; speedup 1.0000x reference)
//
#include <hip/hip_runtime.h>
#include <hip/hip_bf16.h>

#define BTOT 128     // B*T
#define NN   512
#define FIN  128
#define FOUT 64

typedef __attribute__((ext_vector_type(8))) short bf16x8;
typedef __attribute__((ext_vector_type(4))) float f32x4;

static __device__ inline ushort f2bf(float f) {
    __hip_bfloat16 h = __float2bfloat16(f);
    return *(ushort*)&h;
}
static __device__ inline float bf2f(ushort u) {
    uint v = (uint)u << 16;
    return __uint_as_float(v);
}

// ---------- P: W split only (32 blocks) ----------
__global__ void k_prep_w(const float* __restrict__ W, ushort* __restrict__ Whi,
                         ushort* __restrict__ Wlo) {
    int i = blockIdx.x * 256 + threadIdx.x;   // 8192
    float w = W[i];
    ushort hi = f2bf(w);
    Whi[i] = hi;
    Wlo[i] = f2bf(w - bf2f(hi));
}

// ---------- A: h = x @ W^T via bf16x3 MFMA (+ cd-pack blocks 1024..1279) ----------
// feat blocks: 1D bid = ntile*128 + bt => XCD = bt%8 (same XCD k_attn reads).
// x loads fully hoisted (8 independent 16B loads in flight per lane) before
// any conversion/MFMA — fixes the load-serialization that capped HBM depth.
// cd ushort: bits15..1 = w*log2e RNE to 7-bit mantissa; bit0 = "p nonzero";
// stored PRE-SWIZZLED to MFMA A-frag order (see R16).
__global__ __launch_bounds__(256, 4)
void k_feat(const float* __restrict__ x, const ushort* __restrict__ Whi,
            const ushort* __restrict__ Wlo, const float* __restrict__ a,
            ushort* __restrict__ ht, float* __restrict__ srcv,
            float* __restrict__ dstv, const int* __restrict__ adj,
            const float* __restrict__ we, ushort* __restrict__ cds) {
    const int t   = threadIdx.x;
    const int bid = blockIdx.x;

    if (bid >= 1024) {            // ---- cd-pack (runs concurrent with feat) ----
        int lin = ((bid - 1024) * 256 + t) * 4;   // 4 consecutive j
        int i = lin >> 9, j0 = lin & 511;
        int4   a4 = *(const int4*)&adj[lin];
        float4 w4 = *(const float4*)&we[lin];
        ushort o[4];
#pragma unroll
        for (int e = 0; e < 4; ++e) {
            bool  cn = ((const int*)&a4)[e] > 0;
            float w  = ((const float*)&w4)[e];
            if (cn) {
                uint ub = __float_as_uint(w * 1.44269504f);
                uint tt = ub + 0xFFFFu + ((ub >> 17) & 1u);   // RNE @ 7-bit mant
                o[e] = (ushort)(((tt >> 17) << 1) | 1u);
            } else {
                o[e] = (w > 0.f) ? (ushort)0 : (ushort)1;     // p=0 | p=1
            }
        }
        int swz = ((((i >> 4) * 2 + (j0 >> 8)) * 8 + ((j0 >> 5) & 7)) << 9)
                + (((j0 >> 3) & 3) << 7) + ((i & 15) << 3) + (j0 & 7);
        *(uint2*)&cds[swz] = *(uint2*)&o[0];
        return;
    }

    const int bt   = bid & 127;
    const int nt   = bid >> 7;
    const int wv   = t >> 6, lane = t & 63;
    const int r    = lane & 15;          // A-row / B-col within 16; C/D col
    const int kc   = lane >> 4;          // k-chunk; C/D row group
    const int n0   = nt * 64 + wv * 16;

    const float* xrow = x + ((long)bt * NN + n0 + r) * FIN;

    // ---- hoist ALL x loads (8 x 16B per lane, independent, in flight) ----
    f32x4 xv8[8];
#pragma unroll
    for (int ks = 0; ks < 4; ++ks) {
        xv8[2 * ks]     = *(const f32x4*)&xrow[ks * 32 + kc * 8];
        xv8[2 * ks + 1] = *(const f32x4*)&xrow[ks * 32 + kc * 8 + 4];
    }

    // ---- convert all to hi/lo bf16 (exact truncation split) ----
    bf16x8 Ahi[4], Alo[4];
#pragma unroll
    for (int ks = 0; ks < 4; ++ks)
#pragma unroll
        for (int e = 0; e < 8; ++e) {
            float xe = (e < 4) ? xv8[2 * ks][e] : xv8[2 * ks + 1][e - 4];
            uint b = __float_as_uint(xe);
            Ahi[ks][e] = (short)(b >> 16);
            float rr = xe - __uint_as_float(b & 0xFFFF0000u);   // exact
            Alo[ks][e] = (short)(__float_as_uint(rr) >> 16);    // trunc
        }

    f32x4 acc[4] = {{0,0,0,0},{0,0,0,0},{0,0,0,0},{0,0,0,0}};
#pragma unroll
    for (int ks = 0; ks < 4; ++ks)
#pragma unroll
        for (int g = 0; g < 4; ++g) {
            const int wo = (g * 16 + r) * FIN + ks * 32 + kc * 8;
            bf16x8 Bhi = *(const bf16x8*)&Whi[wo];
            bf16x8 Blo = *(const bf16x8*)&Wlo[wo];
            acc[g] = __builtin_amdgcn_mfma_f32_16x16x32_bf16(Ahi[ks], Bhi, acc[g], 0, 0, 0);
            acc[g] = __builtin_amdgcn_mfma_f32_16x16x32_bf16(Alo[ks], Bhi, acc[g], 0, 0, 0);
            acc[g] = __builtin_amdgcn_mfma_f32_16x16x32_bf16(Ahi[ks], Blo, acc[g], 0, 0, 0);
        }

    float a1g[4], a2g[4];
#pragma unroll
    for (int g = 0; g < 4; ++g) {
        a1g[g] = a[g * 16 + r];
        a2g[g] = a[FOUT + g * 16 + r];
    }
    f32x4 s1v = {0,0,0,0}, s2v = {0,0,0,0};
#pragma unroll
    for (int g = 0; g < 4; ++g)
#pragma unroll
        for (int reg = 0; reg < 4; ++reg) {
            s1v[reg] += acc[g][reg] * a1g[g];
            s2v[reg] += acc[g][reg] * a2g[g];
        }
#pragma unroll
    for (int off = 8; off; off >>= 1)
#pragma unroll
        for (int reg = 0; reg < 4; ++reg) {
            s1v[reg] += __shfl_down(s1v[reg], off, 16);
            s2v[reg] += __shfl_down(s2v[reg], off, 16);
        }
    if (r == 0) {
        float4 o1 = make_float4(s1v[0], s1v[1], s1v[2], s1v[3]);
        float4 o2 = make_float4(s2v[0], s2v[1], s2v[2], s2v[3]);
        *(float4*)&srcv[bt * NN + n0 + kc * 4] = o1;
        *(float4*)&dstv[bt * NN + n0 + kc * 4] = o2;
    }

#pragma unroll
    for (int g = 0; g < 4; ++g) {
        uint2 pk;
        pk.x = (uint)f2bf(acc[g][0]) | ((uint)f2bf(acc[g][1]) << 16);
        pk.y = (uint)f2bf(acc[g][2]) | ((uint)f2bf(acc[g][3]) << 16);
        *(uint2*)&ht[(long)bt * (FOUT * NN) + (g * 16 + r) * NN + n0 + kc * 4] = pk;
    }
}

// 8 packed cd ushorts + dst -> A-fragment; pack via v_perm (trunc semantics).
static __device__ inline bf16x8 make_afrag(uint4 c, float4 d0, float4 d1, float si) {
    float dv[8] = {d0.x, d0.y, d0.z, d0.w, d1.x, d1.y, d1.z, d1.w};
    uint  cw[4] = {c.x, c.y, c.z, c.w};
    union { uint u[4]; bf16x8 v; } A;
#pragma unroll
    for (int q = 0; q < 4; ++q) {
        uint u = cw[q];
        float c0 = __uint_as_float((u << 16) & 0xFFFE0000u);
        float c1 = __uint_as_float(u & 0xFFFE0000u);
        float s0 = si + dv[2 * q],     lr0 = fmaxf(s0, 0.01f * s0);
        float s1 = si + dv[2 * q + 1], lr1 = fmaxf(s1, 0.01f * s1);
        float p0 = __builtin_amdgcn_exp2f(c0 * lr0);
        float p1 = __builtin_amdgcn_exp2f(c1 * lr1);
        p0 = (u & 1u)       ? p0 : 0.f;
        p1 = (u & 0x10000u) ? p1 : 0.f;
        // D = p1.hi16 : p0.hi16  (bf16 truncation, 1 instr)
        A.u[q] = __builtin_amdgcn_perm(__float_as_uint(p1), __float_as_uint(p0),
                                       0x07060302u);
    }
    return A.v;
}

// ---------- B: fused att + bf16 MFMA PV (R16-best: 16 rows/wave, coalesced cd) ----
__global__ __launch_bounds__(256, 4)
void k_attn(const ushort* __restrict__ ht, const float* __restrict__ srcv,
            const float* __restrict__ dstv, const ushort* __restrict__ cds,
            float* __restrict__ out) {
    __shared__ ushort hs[64 * 256];   // [o][k-half], granule c8 ^= (o&7)
    __shared__ float dst_s[NN];

    const int t    = threadIdx.x;
    const int bid  = blockIdx.x;
    const int bt   = bid & 127;
    const int it   = bid >> 7;
    const int i0   = it << 6;
    const int lane = t & 63;
    const int wv   = t >> 6;             // 0..3
    const int r16  = lane & 15;
    const int kc   = lane >> 4;          // 0..3
    const int koff = kc * 8;
    const int xr   = r16 & 7;

    const int ri = i0 + wv * 16 + r16;   // my A-row
    const float si = srcv[bt * NN + ri];
    // swizzled cd: block base for (it, wv); per (h, f): + ((h*8+f)<<9) + lane*8
    const ushort* cdb = cds + (((it * 4 + wv) * 2) << 12) + (lane << 3);
    const ushort* htb = ht + (long)bt * (FOUT * NN);

    for (int q = t; q < NN; q += 256) dst_s[q] = dstv[bt * NN + q];

    f32x4 ac0 = {0,0,0,0}, ac1 = {0,0,0,0}, ac2 = {0,0,0,0}, ac3 = {0,0,0,0},
          acd = {0,0,0,0};
    bf16x8 ones;
#pragma unroll
    for (int j = 0; j < 8; ++j) ones[j] = (short)0x3F80;   // bf16 1.0

#pragma unroll
    for (int half = 0; half < 2; ++half) {
        // issue ALL of this half's cd loads now (coalesced 1KB each; complete
        // during staging below)
        uint4 cdv[8];
#pragma unroll
        for (int f = 0; f < 8; ++f)
            cdv[f] = *(const uint4*)&cdb[(half * 8 + f) << 9];

        __syncthreads();   // prev-half hs reads done; dst_s visible (half 0)
        // stage 32KB half-tile: [o][c8] -> hs[o][c8 ^ (o&7)]
#pragma unroll
        for (int q = 0; q < 8; ++q) {
            int idx = q * 256 + t;            // 0..2047
            int o = idx >> 5, c8 = idx & 31;
            float4 v = *(const float4*)&htb[(o << 9) + (half << 8) + (c8 << 3)];
            *(float4*)&hs[(o << 8) + ((c8 ^ (o & 7)) << 3)] = v;
        }
        __syncthreads();

        const int jg = half * 256;
#pragma unroll
        for (int jtl = 0; jtl < 4; ++jtl) {
            const int jgc = jg + jtl * 64;
            float4 d00 = *(float4*)&dst_s[jgc + koff];
            float4 d01 = *(float4*)&dst_s[jgc + koff + 4];
            float4 d10 = *(float4*)&dst_s[jgc + 32 + koff];
            float4 d11 = *(float4*)&dst_s[jgc + 32 + koff + 4];

            bf16x8 A0 = make_afrag(cdv[2 * jtl],     d00, d01, si);   // s2 = 0
            bf16x8 A1 = make_afrag(cdv[2 * jtl + 1], d10, d11, si);   // s2 = 1

#pragma unroll
            for (int s2 = 0; s2 < 2; ++s2) {
                bf16x8 A = s2 ? A1 : A0;
                const int c8v = jtl * 8 + s2 * 4 + kc;
                const int cs  = (c8v ^ xr) << 3;
                bf16x8 b0 = *(bf16x8*)&hs[(( 0 + r16) << 8) + cs];
                bf16x8 b1 = *(bf16x8*)&hs[((16 + r16) << 8) + cs];
                bf16x8 b2 = *(bf16x8*)&hs[((32 + r16) << 8) + cs];
                bf16x8 b3 = *(bf16x8*)&hs[((48 + r16) << 8) + cs];
                __builtin_amdgcn_s_setprio(1);
                ac0 = __builtin_amdgcn_mfma_f32_16x16x32_bf16(A, b0, ac0, 0, 0, 0);
                ac1 = __builtin_amdgcn_mfma_f32_16x16x32_bf16(A, b1, ac1, 0, 0, 0);
                ac2 = __builtin_amdgcn_mfma_f32_16x16x32_bf16(A, b2, ac2, 0, 0, 0);
                ac3 = __builtin_amdgcn_mfma_f32_16x16x32_bf16(A, b3, ac3, 0, 0, 0);
                acd = __builtin_amdgcn_mfma_f32_16x16x32_bf16(A, ones, acd, 0, 0, 0);
                __builtin_amdgcn_s_setprio(0);
            }
        }
    }

    // epilogue: C/D col=r16 (o within g*16), row=kc*4+reg (i within wave's 16)
    float* ob = out + ((long)bt * NN + i0 + wv * 16) * FOUT;
#pragma unroll
    for (int reg = 0; reg < 4; ++reg) {
        float inv = 1.0f / acd[reg];
        const int rw = (kc * 4 + reg) * FOUT + r16;
        __builtin_nontemporal_store(ac0[reg] * inv, &ob[rw +  0]);
        __builtin_nontemporal_store(ac1[reg] * inv, &ob[rw + 16]);
        __builtin_nontemporal_store(ac2[reg] * inv, &ob[rw + 32]);
        __builtin_nontemporal_store(ac3[reg] * inv, &ob[rw + 48]);
    }
}

extern "C" void kernel_launch(void* const* d_in, const int* in_sizes, int n_in,
                              void* d_out, int out_size, void* d_ws, size_t ws_size,
                              hipStream_t stream) {
    const float* x      = (const float*)d_in[0];
    const float* W      = (const float*)d_in[1];
    const float* a      = (const float*)d_in[2];
    const int*   adj    = (const int*)d_in[3];
    const float* adj_we = (const float*)d_in[4];
    float* out = (float*)d_out;

    ushort* Whi  = (ushort*)d_ws;                      // 8192 bf16
    ushort* Wlo  = Whi + FOUT * FIN;                   // 8192 bf16
    ushort* ht   = Wlo + FOUT * FIN;                   // 128*64*512 bf16
    float*  srcv = (float*)(ht + BTOT * FOUT * NN);    // 65536 fp32
    float*  dstv = srcv + BTOT * NN;                   // 65536 fp32
    ushort* cdsw = (ushort*)(dstv + BTOT * NN);        // 262144 ushorts (swizzled)

    hipLaunchKernelGGL(k_prep_w, dim3(32), dim3(256), 0, stream, W, Whi, Wlo);
    hipLaunchKernelGGL(k_feat, dim3(1280), dim3(256), 0, stream,
                       x, Whi, Wlo, a, ht, srcv, dstv, adj, adj_we, cdsw);
    hipLaunchKernelGGL(k_attn, dim3(1024), dim3(256), 0, stream,
                       ht, srcv, dstv, cdsw, out);
}

// Round 19
// 41.596 us; speedup vs baseline: 1.1255x; 1.1255x over previous
//
#include <hip/hip_runtime.h>
#include <hip/hip_bf16.h>

#define BTOT 128     // B*T
#define NN   512
#define FIN  128
#define FOUT 64

typedef __attribute__((ext_vector_type(8))) short bf16x8;
typedef __attribute__((ext_vector_type(4))) float f32x4;

static __device__ inline ushort f2bf(float f) {
    __hip_bfloat16 h = __float2bfloat16(f);
    return *(ushort*)&h;
}

// ---------- A: h = x @ W^T via bf16x3 MFMA (+ cd-pack blocks 1024..1279) ----------
// W is loaded fp32 and hi/lo-split IN REGISTERS (exact truncation split:
// hi=trunc_bf16(w), rr=w-hi exact, lo=trunc_bf16(rr)) — same bytes as the old
// pre-split Whi/Wlo, eliminates the k_prep_w launch entirely.
// feat blocks: bid = ntile*128 + bt => XCD = bt%8 (same XCD k_attn reads).
// cd ushort: bits15..1 = w*log2e RNE to 7-bit mantissa; bit0 = "p nonzero";
// stored PRE-SWIZZLED to MFMA A-frag order (row-group major, see k_attn).
__global__ __launch_bounds__(256, 4)
void k_feat(const float* __restrict__ x, const float* __restrict__ W,
            const float* __restrict__ a,
            ushort* __restrict__ ht, float* __restrict__ srcv,
            float* __restrict__ dstv, const int* __restrict__ adj,
            const float* __restrict__ we, ushort* __restrict__ cds) {
    const int t   = threadIdx.x;
    const int bid = blockIdx.x;

    if (bid >= 1024) {            // ---- cd-pack (concurrent with feat) ----
        int lin = ((bid - 1024) * 256 + t) * 4;   // 4 consecutive j
        int i = lin >> 9, j0 = lin & 511;
        int4   a4 = *(const int4*)&adj[lin];
        float4 w4 = *(const float4*)&we[lin];
        ushort o[4];
#pragma unroll
        for (int e = 0; e < 4; ++e) {
            bool  cn = ((const int*)&a4)[e] > 0;
            float w  = ((const float*)&w4)[e];
            if (cn) {
                uint ub = __float_as_uint(w * 1.44269504f);
                uint tt = ub + 0xFFFFu + ((ub >> 17) & 1u);   // RNE @ 7-bit mant
                o[e] = (ushort)(((tt >> 17) << 1) | 1u);
            } else {
                o[e] = (w > 0.f) ? (ushort)0 : (ushort)1;     // p=0 | p=1
            }
        }
        int swz = ((((i >> 4) * 2 + (j0 >> 8)) * 8 + ((j0 >> 5) & 7)) << 9)
                + (((j0 >> 3) & 3) << 7) + ((i & 15) << 3) + (j0 & 7);
        *(uint2*)&cds[swz] = *(uint2*)&o[0];
        return;
    }

    const int bt   = bid & 127;
    const int nt   = bid >> 7;
    const int wv   = t >> 6, lane = t & 63;
    const int r    = lane & 15;          // A-row / B-col within 16; C/D col
    const int kc   = lane >> 4;          // k-chunk; C/D row group
    const int n0   = nt * 64 + wv * 16;

    const float* xrow = x + ((long)bt * NN + n0 + r) * FIN;

    // hoist ALL x loads (8 x 16B per lane, independent, in flight)
    f32x4 xv8[8];
#pragma unroll
    for (int ks = 0; ks < 4; ++ks) {
        xv8[2 * ks]     = *(const f32x4*)&xrow[ks * 32 + kc * 8];
        xv8[2 * ks + 1] = *(const f32x4*)&xrow[ks * 32 + kc * 8 + 4];
    }

    bf16x8 Ahi[4], Alo[4];
#pragma unroll
    for (int ks = 0; ks < 4; ++ks)
#pragma unroll
        for (int e = 0; e < 8; ++e) {
            float xe = (e < 4) ? xv8[2 * ks][e] : xv8[2 * ks + 1][e - 4];
            uint b = __float_as_uint(xe);
            Ahi[ks][e] = (short)(b >> 16);
            float rr = xe - __uint_as_float(b & 0xFFFF0000u);   // exact
            Alo[ks][e] = (short)(__float_as_uint(rr) >> 16);    // trunc
        }

    f32x4 acc[4] = {{0,0,0,0},{0,0,0,0},{0,0,0,0},{0,0,0,0}};
#pragma unroll
    for (int ks = 0; ks < 4; ++ks)
#pragma unroll
        for (int g = 0; g < 4; ++g) {
            const float* wrow = W + (g * 16 + r) * FIN + ks * 32 + kc * 8;
            f32x4 w0 = *(const f32x4*)&wrow[0];
            f32x4 w1 = *(const f32x4*)&wrow[4];
            bf16x8 Bhi, Blo;
#pragma unroll
            for (int e = 0; e < 8; ++e) {
                float wе = (e < 4) ? w0[e] : w1[e - 4];
                uint b = __float_as_uint(wе);
                Bhi[e] = (short)(b >> 16);
                float rr = wе - __uint_as_float(b & 0xFFFF0000u);   // exact
                Blo[e] = (short)(__float_as_uint(rr) >> 16);        // trunc
            }
            acc[g] = __builtin_amdgcn_mfma_f32_16x16x32_bf16(Ahi[ks], Bhi, acc[g], 0, 0, 0);
            acc[g] = __builtin_amdgcn_mfma_f32_16x16x32_bf16(Alo[ks], Bhi, acc[g], 0, 0, 0);
            acc[g] = __builtin_amdgcn_mfma_f32_16x16x32_bf16(Ahi[ks], Blo, acc[g], 0, 0, 0);
        }

    float a1g[4], a2g[4];
#pragma unroll
    for (int g = 0; g < 4; ++g) {
        a1g[g] = a[g * 16 + r];
        a2g[g] = a[FOUT + g * 16 + r];
    }
    f32x4 s1v = {0,0,0,0}, s2v = {0,0,0,0};
#pragma unroll
    for (int g = 0; g < 4; ++g)
#pragma unroll
        for (int reg = 0; reg < 4; ++reg) {
            s1v[reg] += acc[g][reg] * a1g[g];
            s2v[reg] += acc[g][reg] * a2g[g];
        }
#pragma unroll
    for (int off = 8; off; off >>= 1)
#pragma unroll
        for (int reg = 0; reg < 4; ++reg) {
            s1v[reg] += __shfl_down(s1v[reg], off, 16);
            s2v[reg] += __shfl_down(s2v[reg], off, 16);
        }
    if (r == 0) {
        float4 o1 = make_float4(s1v[0], s1v[1], s1v[2], s1v[3]);
        float4 o2 = make_float4(s2v[0], s2v[1], s2v[2], s2v[3]);
        *(float4*)&srcv[bt * NN + n0 + kc * 4] = o1;
        *(float4*)&dstv[bt * NN + n0 + kc * 4] = o2;
    }

#pragma unroll
    for (int g = 0; g < 4; ++g) {
        uint2 pk;
        pk.x = (uint)f2bf(acc[g][0]) | ((uint)f2bf(acc[g][1]) << 16);
        pk.y = (uint)f2bf(acc[g][2]) | ((uint)f2bf(acc[g][3]) << 16);
        *(uint2*)&ht[(long)bt * (FOUT * NN) + (g * 16 + r) * NN + n0 + kc * 4] = pk;
    }
}

// 8 packed cd ushorts + dst -> A-fragment; pack via v_perm (trunc semantics).
static __device__ inline bf16x8 make_afrag(uint4 c, float4 d0, float4 d1, float si) {
    float dv[8] = {d0.x, d0.y, d0.z, d0.w, d1.x, d1.y, d1.z, d1.w};
    uint  cw[4] = {c.x, c.y, c.z, c.w};
    union { uint u[4]; bf16x8 v; } A;
#pragma unroll
    for (int q = 0; q < 4; ++q) {
        uint u = cw[q];
        float c0 = __uint_as_float((u << 16) & 0xFFFE0000u);
        float c1 = __uint_as_float(u & 0xFFFE0000u);
        float s0 = si + dv[2 * q],     lr0 = fmaxf(s0, 0.01f * s0);
        float s1 = si + dv[2 * q + 1], lr1 = fmaxf(s1, 0.01f * s1);
        float p0 = __builtin_amdgcn_exp2f(c0 * lr0);
        float p1 = __builtin_amdgcn_exp2f(c1 * lr1);
        p0 = (u & 1u)       ? p0 : 0.f;
        p1 = (u & 0x10000u) ? p1 : 0.f;
        // D = p1.hi16 : p0.hi16  (bf16 truncation, 1 instr)
        A.u[q] = __builtin_amdgcn_perm(__float_as_uint(p1), __float_as_uint(p0),
                                       0x07060302u);
    }
    return A.v;
}

// ---------- B: fused att + bf16 MFMA PV — 512 threads (8 waves, 128 i-rows) ----
// grid 512: bid = it*128 + bt (it 0..3) => XCD = bt%8. Halves per-bt hs-staging
// redundancy vs 256-thread blocks (4 blocks/bt instead of 8). LDS 34.8KB,
// 2 blocks/CU (grid-capped) = 16 waves/CU — same occupancy as R16-best.
// All R16 machinery kept: coalesced pre-swizzled cd issued before the staging
// barrier, XOR-swizzled hs, setprio around MFMA cluster.
__global__ __launch_bounds__(512, 2)
void k_attn(const ushort* __restrict__ ht, const float* __restrict__ srcv,
            const float* __restrict__ dstv, const ushort* __restrict__ cds,
            float* __restrict__ out) {
    __shared__ ushort hs[64 * 256];   // [o][k-half], granule c8 ^= (o&7)
    __shared__ float dst_s[NN];

    const int t    = threadIdx.x;
    const int bid  = blockIdx.x;
    const int bt   = bid & 127;
    const int it   = bid >> 7;           // 0..3
    const int i0   = it << 7;            // 128 rows per block
    const int lane = t & 63;
    const int wv   = t >> 6;             // 0..7
    const int r16  = lane & 15;
    const int kc   = lane >> 4;          // 0..3
    const int koff = kc * 8;
    const int xr   = r16 & 7;

    const int ri = i0 + wv * 16 + r16;   // my A-row
    const float si = srcv[bt * NN + ri];
    // swizzled cd: row-group (it*8+wv) owns 16 blocks of 512 ushorts
    const ushort* cdb = cds + (((it * 8 + wv) * 2) << 12) + (lane << 3);
    const ushort* htb = ht + (long)bt * (FOUT * NN);

    for (int q = t; q < NN; q += 512) dst_s[q] = dstv[bt * NN + q];

    f32x4 ac0 = {0,0,0,0}, ac1 = {0,0,0,0}, ac2 = {0,0,0,0}, ac3 = {0,0,0,0},
          acd = {0,0,0,0};
    bf16x8 ones;
#pragma unroll
    for (int j = 0; j < 8; ++j) ones[j] = (short)0x3F80;   // bf16 1.0

#pragma unroll
    for (int half = 0; half < 2; ++half) {
        // issue ALL of this half's cd loads now (coalesced 1KB each; complete
        // during staging below)
        uint4 cdv[8];
#pragma unroll
        for (int f = 0; f < 8; ++f)
            cdv[f] = *(const uint4*)&cdb[(half * 8 + f) << 9];

        __syncthreads();   // prev-half hs reads done; dst_s visible (half 0)
        // stage 32KB half-tile: [o][c8] -> hs[o][c8 ^ (o&7)] (512 threads, 4 iters)
#pragma unroll
        for (int q = 0; q < 4; ++q) {
            int idx = q * 512 + t;            // 0..2047
            int o = idx >> 5, c8 = idx & 31;
            float4 v = *(const float4*)&htb[(o << 9) + (half << 8) + (c8 << 3)];
            *(float4*)&hs[(o << 8) + ((c8 ^ (o & 7)) << 3)] = v;
        }
        __syncthreads();

        const int jg = half * 256;
#pragma unroll
        for (int jtl = 0; jtl < 4; ++jtl) {
            const int jgc = jg + jtl * 64;
            float4 d00 = *(float4*)&dst_s[jgc + koff];
            float4 d01 = *(float4*)&dst_s[jgc + koff + 4];
            float4 d10 = *(float4*)&dst_s[jgc + 32 + koff];
            float4 d11 = *(float4*)&dst_s[jgc + 32 + koff + 4];

            bf16x8 A0 = make_afrag(cdv[2 * jtl],     d00, d01, si);   // s2 = 0
            bf16x8 A1 = make_afrag(cdv[2 * jtl + 1], d10, d11, si);   // s2 = 1

#pragma unroll
            for (int s2 = 0; s2 < 2; ++s2) {
                bf16x8 A = s2 ? A1 : A0;
                const int c8v = jtl * 8 + s2 * 4 + kc;
                const int cs  = (c8v ^ xr) << 3;
                bf16x8 b0 = *(bf16x8*)&hs[(( 0 + r16) << 8) + cs];
                bf16x8 b1 = *(bf16x8*)&hs[((16 + r16) << 8) + cs];
                bf16x8 b2 = *(bf16x8*)&hs[((32 + r16) << 8) + cs];
                bf16x8 b3 = *(bf16x8*)&hs[((48 + r16) << 8) + cs];
                __builtin_amdgcn_s_setprio(1);
                ac0 = __builtin_amdgcn_mfma_f32_16x16x32_bf16(A, b0, ac0, 0, 0, 0);
                ac1 = __builtin_amdgcn_mfma_f32_16x16x32_bf16(A, b1, ac1, 0, 0, 0);
                ac2 = __builtin_amdgcn_mfma_f32_16x16x32_bf16(A, b2, ac2, 0, 0, 0);
                ac3 = __builtin_amdgcn_mfma_f32_16x16x32_bf16(A, b3, ac3, 0, 0, 0);
                acd = __builtin_amdgcn_mfma_f32_16x16x32_bf16(A, ones, acd, 0, 0, 0);
                __builtin_amdgcn_s_setprio(0);
            }
        }
    }

    // epilogue: C/D col=r16 (o within g*16), row=kc*4+reg (i within wave's 16)
    float* ob = out + ((long)bt * NN + i0 + wv * 16) * FOUT;
#pragma unroll
    for (int reg = 0; reg < 4; ++reg) {
        float inv = 1.0f / acd[reg];
        const int rw = (kc * 4 + reg) * FOUT + r16;
        __builtin_nontemporal_store(ac0[reg] * inv, &ob[rw +  0]);
        __builtin_nontemporal_store(ac1[reg] * inv, &ob[rw + 16]);
        __builtin_nontemporal_store(ac2[reg] * inv, &ob[rw + 32]);
        __builtin_nontemporal_store(ac3[reg] * inv, &ob[rw + 48]);
    }
}

extern "C" void kernel_launch(void* const* d_in, const int* in_sizes, int n_in,
                              void* d_out, int out_size, void* d_ws, size_t ws_size,
                              hipStream_t stream) {
    const float* x      = (const float*)d_in[0];
    const float* W      = (const float*)d_in[1];
    const float* a      = (const float*)d_in[2];
    const int*   adj    = (const int*)d_in[3];
    const float* adj_we = (const float*)d_in[4];
    float* out = (float*)d_out;

    ushort* ht   = (ushort*)d_ws;                      // 128*64*512 bf16
    float*  srcv = (float*)(ht + BTOT * FOUT * NN);    // 65536 fp32
    float*  dstv = srcv + BTOT * NN;                   // 65536 fp32
    ushort* cdsw = (ushort*)(dstv + BTOT * NN);        // 262144 ushorts (swizzled)

    hipLaunchKernelGGL(k_feat, dim3(1280), dim3(256), 0, stream,
                       x, W, a, ht, srcv, dstv, adj, adj_we, cdsw);
    hipLaunchKernelGGL(k_attn, dim3(512), dim3(512), 0, stream,
                       ht, srcv, dstv, cdsw, out);
}

// Round 21
// 41.422 us; speedup vs baseline: 1.1302x; 1.0042x over previous
//
#include <hip/hip_runtime.h>
#include <hip/hip_bf16.h>

#define BTOT 128     // B*T
#define NN   512
#define FIN  128
#define FOUT 64

typedef __attribute__((ext_vector_type(8))) short bf16x8;
typedef __attribute__((ext_vector_type(4))) float f32x4;

static __device__ inline ushort f2bf(float f) {
    __hip_bfloat16 h = __float2bfloat16(f);
    return *(ushort*)&h;
}

// ---------- A: h = x @ W^T via bf16x3 MFMA (+ cd-pack blocks 1024..1279) ----------
// W is loaded fp32 and hi/lo-split IN REGISTERS (exact truncation split:
// hi=trunc_bf16(w), rr=w-hi exact, lo=trunc_bf16(rr)).
// feat blocks: bid = ntile*128 + bt => XCD = bt%8 (same XCD k_attn reads).
// cd ushort: bits15..1 = w*log2e RNE to 7-bit mantissa; bit0 = "p nonzero";
// stored PRE-SWIZZLED to MFMA A-frag order (row-group major, see k_attn).
// NOTE: cds is all-to-all across XCDs — the k_feat->k_attn kernel boundary is
// what guarantees its cross-XCD visibility (R20's fused grid.sync version went
// stale; see G16). Do not fuse these kernels.
__global__ __launch_bounds__(256, 4)
void k_feat(const float* __restrict__ x, const float* __restrict__ W,
            const float* __restrict__ a,
            ushort* __restrict__ ht, float* __restrict__ srcv,
            float* __restrict__ dstv, const int* __restrict__ adj,
            const float* __restrict__ we, ushort* __restrict__ cds) {
    const int t   = threadIdx.x;
    const int bid = blockIdx.x;

    if (bid >= 1024) {            // ---- cd-pack (concurrent with feat) ----
        int lin = ((bid - 1024) * 256 + t) * 4;   // 4 consecutive j
        int i = lin >> 9, j0 = lin & 511;
        int4   a4 = *(const int4*)&adj[lin];
        float4 w4 = *(const float4*)&we[lin];
        ushort o[4];
#pragma unroll
        for (int e = 0; e < 4; ++e) {
            bool  cn = ((const int*)&a4)[e] > 0;
            float w  = ((const float*)&w4)[e];
            if (cn) {
                uint ub = __float_as_uint(w * 1.44269504f);
                uint tt = ub + 0xFFFFu + ((ub >> 17) & 1u);   // RNE @ 7-bit mant
                o[e] = (ushort)(((tt >> 17) << 1) | 1u);
            } else {
                o[e] = (w > 0.f) ? (ushort)0 : (ushort)1;     // p=0 | p=1
            }
        }
        int swz = ((((i >> 4) * 2 + (j0 >> 8)) * 8 + ((j0 >> 5) & 7)) << 9)
                + (((j0 >> 3) & 3) << 7) + ((i & 15) << 3) + (j0 & 7);
        *(uint2*)&cds[swz] = *(uint2*)&o[0];
        return;
    }

    const int bt   = bid & 127;
    const int nt   = bid >> 7;
    const int wv   = t >> 6, lane = t & 63;
    const int r    = lane & 15;          // A-row / B-col within 16; C/D col
    const int kc   = lane >> 4;          // k-chunk; C/D row group
    const int n0   = nt * 64 + wv * 16;

    const float* xrow = x + ((long)bt * NN + n0 + r) * FIN;

    // hoist ALL x loads (8 x 16B per lane, independent, in flight)
    f32x4 xv8[8];
#pragma unroll
    for (int ks = 0; ks < 4; ++ks) {
        xv8[2 * ks]     = *(const f32x4*)&xrow[ks * 32 + kc * 8];
        xv8[2 * ks + 1] = *(const f32x4*)&xrow[ks * 32 + kc * 8 + 4];
    }

    bf16x8 Ahi[4], Alo[4];
#pragma unroll
    for (int ks = 0; ks < 4; ++ks)
#pragma unroll
        for (int e = 0; e < 8; ++e) {
            float xe = (e < 4) ? xv8[2 * ks][e] : xv8[2 * ks + 1][e - 4];
            uint b = __float_as_uint(xe);
            Ahi[ks][e] = (short)(b >> 16);
            float rr = xe - __uint_as_float(b & 0xFFFF0000u);   // exact
            Alo[ks][e] = (short)(__float_as_uint(rr) >> 16);    // trunc
        }

    f32x4 acc[4] = {{0,0,0,0},{0,0,0,0},{0,0,0,0},{0,0,0,0}};
#pragma unroll
    for (int ks = 0; ks < 4; ++ks)
#pragma unroll
        for (int g = 0; g < 4; ++g) {
            const float* wrow = W + (g * 16 + r) * FIN + ks * 32 + kc * 8;
            f32x4 w0 = *(const f32x4*)&wrow[0];
            f32x4 w1 = *(const f32x4*)&wrow[4];
            bf16x8 Bhi, Blo;
#pragma unroll
            for (int e = 0; e < 8; ++e) {
                float wx = (e < 4) ? w0[e] : w1[e - 4];
                uint b = __float_as_uint(wx);
                Bhi[e] = (short)(b >> 16);
                float rr = wx - __uint_as_float(b & 0xFFFF0000u);   // exact
                Blo[e] = (short)(__float_as_uint(rr) >> 16);        // trunc
            }
            acc[g] = __builtin_amdgcn_mfma_f32_16x16x32_bf16(Ahi[ks], Bhi, acc[g], 0, 0, 0);
            acc[g] = __builtin_amdgcn_mfma_f32_16x16x32_bf16(Alo[ks], Bhi, acc[g], 0, 0, 0);
            acc[g] = __builtin_amdgcn_mfma_f32_16x16x32_bf16(Ahi[ks], Blo, acc[g], 0, 0, 0);
        }

    float a1g[4], a2g[4];
#pragma unroll
    for (int g = 0; g < 4; ++g) {
        a1g[g] = a[g * 16 + r];
        a2g[g] = a[FOUT + g * 16 + r];
    }
    f32x4 s1v = {0,0,0,0}, s2v = {0,0,0,0};
#pragma unroll
    for (int g = 0; g < 4; ++g)
#pragma unroll
        for (int reg = 0; reg < 4; ++reg) {
            s1v[reg] += acc[g][reg] * a1g[g];
            s2v[reg] += acc[g][reg] * a2g[g];
        }
#pragma unroll
    for (int off = 8; off; off >>= 1)
#pragma unroll
        for (int reg = 0; reg < 4; ++reg) {
            s1v[reg] += __shfl_down(s1v[reg], off, 16);
            s2v[reg] += __shfl_down(s2v[reg], off, 16);
        }
    if (r == 0) {
        float4 o1 = make_float4(s1v[0], s1v[1], s1v[2], s1v[3]);
        float4 o2 = make_float4(s2v[0], s2v[1], s2v[2], s2v[3]);
        *(float4*)&srcv[bt * NN + n0 + kc * 4] = o1;
        *(float4*)&dstv[bt * NN + n0 + kc * 4] = o2;
    }

#pragma unroll
    for (int g = 0; g < 4; ++g) {
        uint2 pk;
        pk.x = (uint)f2bf(acc[g][0]) | ((uint)f2bf(acc[g][1]) << 16);
        pk.y = (uint)f2bf(acc[g][2]) | ((uint)f2bf(acc[g][3]) << 16);
        *(uint2*)&ht[(long)bt * (FOUT * NN) + (g * 16 + r) * NN + n0 + kc * 4] = pk;
    }
}

// 8 packed cd ushorts + dst -> A-fragment; pack via v_perm (trunc semantics).
static __device__ inline bf16x8 make_afrag(uint4 c, float4 d0, float4 d1, float si) {
    float dv[8] = {d0.x, d0.y, d0.z, d0.w, d1.x, d1.y, d1.z, d1.w};
    uint  cw[4] = {c.x, c.y, c.z, c.w};
    union { uint u[4]; bf16x8 v; } A;
#pragma unroll
    for (int q = 0; q < 4; ++q) {
        uint u = cw[q];
        float c0 = __uint_as_float((u << 16) & 0xFFFE0000u);
        float c1 = __uint_as_float(u & 0xFFFE0000u);
        float s0 = si + dv[2 * q],     lr0 = fmaxf(s0, 0.01f * s0);
        float s1 = si + dv[2 * q + 1], lr1 = fmaxf(s1, 0.01f * s1);
        float p0 = __builtin_amdgcn_exp2f(c0 * lr0);
        float p1 = __builtin_amdgcn_exp2f(c1 * lr1);
        p0 = (u & 1u)       ? p0 : 0.f;
        p1 = (u & 0x10000u) ? p1 : 0.f;
        // D = p1.hi16 : p0.hi16  (bf16 truncation, 1 instr)
        A.u[q] = __builtin_amdgcn_perm(__float_as_uint(p1), __float_as_uint(p0),
                                       0x07060302u);
    }
    return A.v;
}

// ---------- B: fused att + bf16 MFMA PV — 512 threads (8 waves, 128 i-rows) ----
// grid 512: bid = it*128 + bt (it 0..3) => XCD = bt%8. Halves per-bt hs-staging
// redundancy vs 256-thread blocks (4 blocks/bt instead of 8). LDS 34.8KB,
// 2 blocks/CU = 16 waves/CU. Coalesced pre-swizzled cd issued before the
// staging barrier, XOR-swizzled hs, setprio around MFMA cluster, den via 5th
// MFMA (B = splat 1.0), NT stores for out.
__global__ __launch_bounds__(512, 2)
void k_attn(const ushort* __restrict__ ht, const float* __restrict__ srcv,
            const float* __restrict__ dstv, const ushort* __restrict__ cds,
            float* __restrict__ out) {
    __shared__ ushort hs[64 * 256];   // [o][k-half], granule c8 ^= (o&7)
    __shared__ float dst_s[NN];

    const int t    = threadIdx.x;
    const int bid  = blockIdx.x;
    const int bt   = bid & 127;
    const int it   = bid >> 7;           // 0..3
    const int i0   = it << 7;            // 128 rows per block
    const int lane = t & 63;
    const int wv   = t >> 6;             // 0..7
    const int r16  = lane & 15;
    const int kc   = lane >> 4;          // 0..3
    const int koff = kc * 8;
    const int xr   = r16 & 7;

    const int ri = i0 + wv * 16 + r16;   // my A-row
    const float si = srcv[bt * NN + ri];
    // swizzled cd: row-group (it*8+wv) owns 16 blocks of 512 ushorts
    const ushort* cdb = cds + (((it * 8 + wv) * 2) << 12) + (lane << 3);
    const ushort* htb = ht + (long)bt * (FOUT * NN);

    for (int q = t; q < NN; q += 512) dst_s[q] = dstv[bt * NN + q];

    f32x4 ac0 = {0,0,0,0}, ac1 = {0,0,0,0}, ac2 = {0,0,0,0}, ac3 = {0,0,0,0},
          acd = {0,0,0,0};
    bf16x8 ones;
#pragma unroll
    for (int j = 0; j < 8; ++j) ones[j] = (short)0x3F80;   // bf16 1.0

#pragma unroll
    for (int half = 0; half < 2; ++half) {
        // issue ALL of this half's cd loads now (coalesced 1KB each; complete
        // during staging below)
        uint4 cdv[8];
#pragma unroll
        for (int f = 0; f < 8; ++f)
            cdv[f] = *(const uint4*)&cdb[(half * 8 + f) << 9];

        __syncthreads();   // prev-half hs reads done; dst_s visible (half 0)
        // stage 32KB half-tile: [o][c8] -> hs[o][c8 ^ (o&7)] (512 threads, 4 iters)
#pragma unroll
        for (int q = 0; q < 4; ++q) {
            int idx = q * 512 + t;            // 0..2047
            int o = idx >> 5, c8 = idx & 31;
            float4 v = *(const float4*)&htb[(o << 9) + (half << 8) + (c8 << 3)];
            *(float4*)&hs[(o << 8) + ((c8 ^ (o & 7)) << 3)] = v;
        }
        __syncthreads();

        const int jg = half * 256;
#pragma unroll
        for (int jtl = 0; jtl < 4; ++jtl) {
            const int jgc = jg + jtl * 64;
            float4 d00 = *(float4*)&dst_s[jgc + koff];
            float4 d01 = *(float4*)&dst_s[jgc + koff + 4];
            float4 d10 = *(float4*)&dst_s[jgc + 32 + koff];
            float4 d11 = *(float4*)&dst_s[jgc + 32 + koff + 4];

            bf16x8 A0 = make_afrag(cdv[2 * jtl],     d00, d01, si);   // s2 = 0
            bf16x8 A1 = make_afrag(cdv[2 * jtl + 1], d10, d11, si);   // s2 = 1

#pragma unroll
            for (int s2 = 0; s2 < 2; ++s2) {
                bf16x8 A = s2 ? A1 : A0;
                const int c8v = jtl * 8 + s2 * 4 + kc;
                const int cs  = (c8v ^ xr) << 3;
                bf16x8 b0 = *(bf16x8*)&hs[(( 0 + r16) << 8) + cs];
                bf16x8 b1 = *(bf16x8*)&hs[((16 + r16) << 8) + cs];
                bf16x8 b2 = *(bf16x8*)&hs[((32 + r16) << 8) + cs];
                bf16x8 b3 = *(bf16x8*)&hs[((48 + r16) << 8) + cs];
                __builtin_amdgcn_s_setprio(1);
                ac0 = __builtin_amdgcn_mfma_f32_16x16x32_bf16(A, b0, ac0, 0, 0, 0);
                ac1 = __builtin_amdgcn_mfma_f32_16x16x32_bf16(A, b1, ac1, 0, 0, 0);
                ac2 = __builtin_amdgcn_mfma_f32_16x16x32_bf16(A, b2, ac2, 0, 0, 0);
                ac3 = __builtin_amdgcn_mfma_f32_16x16x32_bf16(A, b3, ac3, 0, 0, 0);
                acd = __builtin_amdgcn_mfma_f32_16x16x32_bf16(A, ones, acd, 0, 0, 0);
                __builtin_amdgcn_s_setprio(0);
            }
        }
    }

    // epilogue: C/D col=r16 (o within g*16), row=kc*4+reg (i within wave's 16)
    float* ob = out + ((long)bt * NN + i0 + wv * 16) * FOUT;
#pragma unroll
    for (int reg = 0; reg < 4; ++reg) {
        float inv = 1.0f / acd[reg];
        const int rw = (kc * 4 + reg) * FOUT + r16;
        __builtin_nontemporal_store(ac0[reg] * inv, &ob[rw +  0]);
        __builtin_nontemporal_store(ac1[reg] * inv, &ob[rw + 16]);
        __builtin_nontemporal_store(ac2[reg] * inv, &ob[rw + 32]);
        __builtin_nontemporal_store(ac3[reg] * inv, &ob[rw + 48]);
    }
}

extern "C" void kernel_launch(void* const* d_in, const int* in_sizes, int n_in,
                              void* d_out, int out_size, void* d_ws, size_t ws_size,
                              hipStream_t stream) {
    const float* x      = (const float*)d_in[0];
    const float* W      = (const float*)d_in[1];
    const float* a      = (const float*)d_in[2];
    const int*   adj    = (const int*)d_in[3];
    const float* adj_we = (const float*)d_in[4];
    float* out = (float*)d_out;

    ushort* ht   = (ushort*)d_ws;                      // 128*64*512 bf16
    float*  srcv = (float*)(ht + BTOT * FOUT * NN);    // 65536 fp32
    float*  dstv = srcv + BTOT * NN;                   // 65536 fp32
    ushort* cdsw = (ushort*)(dstv + BTOT * NN);        // 262144 ushorts (swizzled)

    hipLaunchKernelGGL(k_feat, dim3(1280), dim3(256), 0, stream,
                       x, W, a, ht, srcv, dstv, adj, adj_we, cdsw);
    hipLaunchKernelGGL(k_attn, dim3(512), dim3(512), 0, stream,
                       ht, srcv, dstv, cdsw, out);
}